// Round 4
// baseline (164.842 us; speedup 1.0000x reference)
//
#include <hip/hip_runtime.h>
#include <math.h>

// B=4, T=512, IDIM=128, HDIM=1024, CDIM=256
#define NBLK  2048            // one row per block, 4 waves per block
#define NITER 4
#define IGNORE_OUT 10000.0f
#define LOG2E 1.44269504088896340736f

__device__ __forceinline__ float readlanef(float v, int lane){
  return __int_as_float(__builtin_amdgcn_readlane(__float_as_int(v), lane));
}

// ---- DPP wave primitives (gfx9 ladder: row_shr 1/2/4/8, bcast15->rows1,3, bcast31->rows2,3) ----
__device__ __forceinline__ float waveScanInc(float v){
  v += __int_as_float(__builtin_amdgcn_update_dpp(0, __float_as_int(v), 0x111, 0xF, 0xF, true));
  v += __int_as_float(__builtin_amdgcn_update_dpp(0, __float_as_int(v), 0x112, 0xF, 0xF, true));
  v += __int_as_float(__builtin_amdgcn_update_dpp(0, __float_as_int(v), 0x114, 0xF, 0xF, true));
  v += __int_as_float(__builtin_amdgcn_update_dpp(0, __float_as_int(v), 0x118, 0xF, 0xF, true));
  v += __int_as_float(__builtin_amdgcn_update_dpp(0, __float_as_int(v), 0x142, 0xA, 0xF, true));
  v += __int_as_float(__builtin_amdgcn_update_dpp(0, __float_as_int(v), 0x143, 0xC, 0xF, true));
  return v;                                // lane l = sum of lanes 0..l
}
__device__ __forceinline__ float waveSum(float v){
  return readlanef(waveScanInc(v), 63);
}
__device__ __forceinline__ void waveArgmax(float &v, int &i){
#define AMSTEP(ctrl, rm) { \
    float ov = __int_as_float(__builtin_amdgcn_update_dpp(__float_as_int(v), __float_as_int(v), ctrl, rm, 0xF, false)); \
    int   oi = __builtin_amdgcn_update_dpp(i, i, ctrl, rm, 0xF, false); \
    bool take = (ov > v) || (ov == v && oi < i); \
    v = take ? ov : v; i = take ? oi : i; }
  AMSTEP(0x111, 0xF) AMSTEP(0x112, 0xF) AMSTEP(0x114, 0xF)
  AMSTEP(0x118, 0xF) AMSTEP(0x142, 0xA) AMSTEP(0x143, 0xC)
#undef AMSTEP
  v = readlanef(v, 63);
  i = __builtin_amdgcn_readlane(i, 63);
}
// paired gather: a = vec[idx], b = vec[idx+64] (0 outside [0,128)); 2 bpermutes total
__device__ __forceinline__ void gatherPair(float v0, float v1, int idx, float &a, float &b){
  int c = idx & 63;
  float g0 = __shfl(v0, c, 64);
  float g1 = __shfl(v1, c, 64);
  a = ((unsigned)idx < 128u) ? ((idx & 64) ? g1 : g0) : 0.f;
  int idx2 = idx + 64;
  b = ((unsigned)idx2 < 128u) ? ((idx2 & 64) ? g1 : g0) : 0.f;
}

// ---------- prep kernel: M4[i] = w2[:, i*256:(i+1)*256] @ w1[i*256:(i+1)*256, :] ----------
// 256 threads: h = tid>>7 splits the 256-deep K range in half, LDS combine.
__global__ __launch_bounds__(256)
void prepK(const float* __restrict__ w1, const float* __restrict__ b1,
           const float* __restrict__ w2, const float* __restrict__ b2,
           float* __restrict__ M4, float* __restrict__ biasT, int* __restrict__ ticket){
  const int blk = blockIdx.x;
  const int tid = threadIdx.x;
  const int u = tid & 127, h = tid >> 7;
  __shared__ float part[256];
  if (blk < 512){
    int i = blk >> 7, o = blk & 127;
    const float* w1p = w1 + (i * 256 + h * 128) * 128 + u;   // coalesced over d=u
    const float* w2p = w2 + o * 1024 + i * 256 + h * 128;    // thread-uniform
    float a0 = 0.f, a1 = 0.f, a2 = 0.f, a3 = 0.f;
    #pragma unroll 8
    for (int c = 0; c < 128; c += 4){
      a0 = fmaf(w1p[(c + 0) * 128], w2p[c + 0], a0);
      a1 = fmaf(w1p[(c + 1) * 128], w2p[c + 1], a1);
      a2 = fmaf(w1p[(c + 2) * 128], w2p[c + 2], a2);
      a3 = fmaf(w1p[(c + 3) * 128], w2p[c + 3], a3);
    }
    part[tid] = (a0 + a1) + (a2 + a3);
    __syncthreads();
    if (h == 0) M4[i * 16384 + (u >> 2) * 512 + o * 4 + (u & 3)] = part[u] + part[128 + u];
  } else if (blk < 516){
    int i = blk - 512;
    const float* w2p = w2 + u * 1024 + i * 256 + h * 128;
    const float* b1p = b1 + i * 256 + h * 128;
    float a0 = h ? 0.f : b2[u], a1 = 0.f, a2 = 0.f, a3 = 0.f;
    #pragma unroll 8
    for (int c = 0; c < 128; c += 4){
      a0 = fmaf(b1p[c + 0], w2p[c + 0], a0);
      a1 = fmaf(b1p[c + 1], w2p[c + 1], a1);
      a2 = fmaf(b1p[c + 2], w2p[c + 2], a2);
      a3 = fmaf(b1p[c + 3], w2p[c + 3], a3);
    }
    part[tid] = (a0 + a1) + (a2 + a3);
    __syncthreads();
    if (h == 0) biasT[i * 128 + u] = part[u] + part[128 + u];
  } else {
    if (tid == 0) *ticket = 0;
  }
}

// M-group load/consume macros — NAMED float4 scalars (no arrays: spill-proof).
// MpW is pre-offset per wave (j-half) and per thread (output o); local group gg 0..3.
#define MLD(d0, d1, d2, d3, gg) \
  d0 = MpW[((gg) * 4 + 0) * 128]; d1 = MpW[((gg) * 4 + 1) * 128]; \
  d2 = MpW[((gg) * 4 + 2) * 128]; d3 = MpW[((gg) * 4 + 3) * 128];
#define MFM(m0, m1, m2, m3, src, kb) \
  a0 = fmaf((m0).x, readlanef(src, (kb) + 0), a0);  a0 = fmaf((m0).y, readlanef(src, (kb) + 1), a0); \
  a0 = fmaf((m0).z, readlanef(src, (kb) + 2), a0);  a0 = fmaf((m0).w, readlanef(src, (kb) + 3), a0); \
  a1 = fmaf((m1).x, readlanef(src, (kb) + 4), a1);  a1 = fmaf((m1).y, readlanef(src, (kb) + 5), a1); \
  a1 = fmaf((m1).z, readlanef(src, (kb) + 6), a1);  a1 = fmaf((m1).w, readlanef(src, (kb) + 7), a1); \
  a2 = fmaf((m2).x, readlanef(src, (kb) + 8), a2);  a2 = fmaf((m2).y, readlanef(src, (kb) + 9), a2); \
  a2 = fmaf((m2).z, readlanef(src, (kb) +10), a2);  a2 = fmaf((m2).w, readlanef(src, (kb) +11), a2); \
  a3 = fmaf((m3).x, readlanef(src, (kb) +12), a3);  a3 = fmaf((m3).y, readlanef(src, (kb) +13), a3); \
  a3 = fmaf((m3).z, readlanef(src, (kb) +14), a3);  a3 = fmaf((m3).w, readlanef(src, (kb) +15), a3);

// ---------- main kernel: 4 waves/row (2x2 corr split, k-split MLP), 2 barriers/iter ----------
// wave w = 2*jh + th : th = t-half (t = 64*th + l), jh = j-half (j in [64*jh, 64*jh+64)).
// Window value (t, j) = ydW[w][(255 - t) + j] where ydW[w][128+k] = ydW[w][256+k] = y_res[k]
// (per-wave private copy -> the end-of-iteration barrier is eliminated).
// Corr partial-sum grouping is bit-identical to the round-3 kernel (verified passing).
__global__ __launch_bounds__(256, 8)
void mainK(const float* __restrict__ x, const float* __restrict__ y,
           const float* __restrict__ M4, const float* __restrict__ biasT,
           unsigned long long* __restrict__ partials, int* __restrict__ ticket,
           float* __restrict__ out){
  __shared__ float ydW[4][384];   // per-wave y window copies
  __shared__ float Ab[64], Bb[64], Cb[64], Db[64], Pb[64], Qb[64];  // corr partials
  __shared__ float mlpB[256];     // MLP half-partials: [o]=low-k, [128+o]=high-k
  __shared__ float sL[4], sC[4];
  __shared__ int   sOld;

  const int u  = threadIdx.x;     // 0..255
  const int l  = u & 63;
  const int w  = u >> 6;          // wave 0..3
  const int th = w & 1;           // t-half
  const int jh = w >> 1;          // j-half (also MLP k-half)
  const int o  = u & 127;         // MLP output index
  const long base = (long)blockIdx.x * 128;

  float xlo = x[base + l], xhi = x[base + 64 + l];
  float ylo = y[base + l], yhi = y[base + 64 + l];
  const bool mask_l = (ylo == IGNORE_OUT);
  const bool mask_h = (yhi == IGNORE_OUT);
  float cnt = (w == 0) ? (mask_l ? 0.f : 1.f) : ((w == 1) ? (mask_h ? 0.f : 1.f) : 0.f);
  float lossAcc = 0.f;

  // own-wave window copy (same-wave RAW via LDS: no barrier needed)
  float* ydw = ydW[w];
  ydw[128 + l] = ylo; ydw[192 + l] = yhi; ydw[256 + l] = ylo; ydw[320 + l] = yhi;
  const float* wp = ydw + (255 - 64 * th + 64 * jh) - l;   // quadrant window base

  for (int i = 0; i < NITER; ++i){
    const float4* MpW = (const float4*)(M4 + (size_t)i * 16384) + jh * 2048 + o;
    float bias_l = biasT[i * 128 + l];          // both halves' bias (phase D)
    float bias_h = biasT[i * 128 + 64 + l];

    // ---- phase A: corr quadrant (64 b32 LDS reads, readlane broadcasts, 4-way split;
    //      masked prefix only on diagonal waves 0,3) + scans (dup, all waves) ----
    const float xsrc = jh ? xhi : xlo;
    float s0=0.f,s1=0.f,s2=0.f,s3=0.f, p0=0.f,p1=0.f,p2=0.f,p3=0.f;
    if (w == 0 || w == 3){
      #pragma unroll
      for (int j = 0; j < 64; j += 4){
        float wv0 = wp[j], wv1 = wp[j+1], wv2 = wp[j+2], wv3 = wp[j+3];
        float x0 = readlanef(xsrc, j),   x1 = readlanef(xsrc, j+1);
        float x2 = readlanef(xsrc, j+2), x3 = readlanef(xsrc, j+3);
        s0 = fmaf(wv0, x0, s0); s1 = fmaf(wv1, x1, s1);
        s2 = fmaf(wv2, x2, s2); s3 = fmaf(wv3, x3, s3);
        p0 = fmaf((l >= j    ) ? wv0 : 0.f, x0, p0);
        p1 = fmaf((l >= j + 1) ? wv1 : 0.f, x1, p1);
        p2 = fmaf((l >= j + 2) ? wv2 : 0.f, x2, p2);
        p3 = fmaf((l >= j + 3) ? wv3 : 0.f, x3, p3);
      }
    } else {
      #pragma unroll
      for (int j = 0; j < 64; j += 4){
        float wv0 = wp[j], wv1 = wp[j+1], wv2 = wp[j+2], wv3 = wp[j+3];
        s0 = fmaf(wv0, readlanef(xsrc, j),   s0);
        s1 = fmaf(wv1, readlanef(xsrc, j+1), s1);
        s2 = fmaf(wv2, readlanef(xsrc, j+2), s2);
        s3 = fmaf(wv3, readlanef(xsrc, j+3), s3);
      }
    }
    float S = (s0 + s1) + (s2 + s3);
    float P = (p0 + p1) + (p2 + p3);
    if      (w == 0){ Ab[l] = S; Pb[l] = P; }
    else if (w == 1){ Bb[l] = S; }
    else if (w == 2){ Cb[l] = S; }
    else            { Db[l] = S; Qb[l] = P; }

    // scans (duplicated in every wave; identical arithmetic to r3 per t-half)
    float v_lo = waveScanInc(xlo * xlo);
    float slo  = readlanef(v_lo, 63);
    float v_hi = waveScanInc(xhi * xhi);
    float shi  = readlanef(v_hi, 63);
    float total = slo + shi;
    float ny2 = waveSum(ylo * ylo + yhi * yhi);

    __syncthreads();                       // B_a: corr partials visible

    // ---- phase B: all waves compute all 256 sims + full argmax in-wave ----
    float SA = Ab[l], SB = Bb[l], SC = Cb[l], SD = Db[l], PP = Pb[l], QQ = Qb[l];
    float nt_l = SA + SC, n1_l = PP;        // t = l
    float nt_h = SB + SD, n1_h = SB + QQ;   // t = 64 + l
    float pref_l = v_lo;                    // inclusive x^2 prefix at t=l
    float pref_h = v_hi + slo;              // at t=64+l (same grouping as r3)
    int sstar;
    {
      bool yz = (ny2 == 0.f);
      float rNY = __builtin_amdgcn_rsqf(ny2);
      float nx_l = fmaxf(total - pref_l, 0.f);
      float nx_h = fmaxf(total - pref_h, 0.f);
      float s1l = (yz || pref_l == 0.f) ? 0.f : n1_l * __builtin_amdgcn_rsqf(pref_l) * rNY;
      float s2l = (yz || nx_l   == 0.f) ? 0.f : (nt_l - n1_l) * __builtin_amdgcn_rsqf(nx_l) * rNY;
      float s1h = (yz || pref_h == 0.f) ? 0.f : n1_h * __builtin_amdgcn_rsqf(pref_h) * rNY;
      float s2h = (yz || nx_h   == 0.f) ? 0.f : (nt_h - n1_h) * __builtin_amdgcn_rsqf(nx_h) * rNY;
      if (l == 63) s2h = -INFINITY;        // shift 255 doesn't exist
      // 4 candidates in increasing shift order -> strict > keeps first-max semantics
      float bv = s1l; int bi = l;
      if (s1h > bv){ bv = s1h; bi = 64 + l; }
      if (s2l > bv){ bv = s2l; bi = 128 + l; }
      if (s2h > bv){ bv = s2h; bi = 192 + l; }
      waveArgmax(bv, bi);
      sstar = bi;
    }

    // ---- MLP prefetch (this wave's k-half, groups 0,1): hidden under softmax ----
    float4 A0, A1, A2, A3, B0, B1, B2, B3;
    MLD(A0, A1, A2, A3, 0)
    MLD(B0, B1, B2, B3, 1)

    // ---- x_aug + detached softmax + x_res update (duplicated in every wave) ----
    float xa, xb;
    gatherPair(xlo, xhi, sstar + l - 127, xa, xb);
    float ea = __builtin_amdgcn_exp2f(xa * ylo * LOG2E);
    float eb = __builtin_amdgcn_exp2f(xb * yhi * LOG2E);
    float rse = __builtin_amdgcn_rcpf(waveSum(ea + eb));
    float wlo = xa * (ea * rse), whi = xb * (eb * rse);   // xatt
    {
      float ga, gb;
      gatherPair(wlo, whi, l + 127 - sstar, ga, gb);
      xlo -= ga; xhi -= gb;
    }

    // ---- phase C: MLP half-dot (64 k's), 2 rotating buffers ----
    {
      const float wsrc = jh ? whi : wlo;
      float a0 = 0.f, a1 = 0.f, a2 = 0.f, a3 = 0.f;
      MFM(A0, A1, A2, A3, wsrc, 0)   MLD(A0, A1, A2, A3, 2)
      MFM(B0, B1, B2, B3, wsrc, 16)  MLD(B0, B1, B2, B3, 3)
      MFM(A0, A1, A2, A3, wsrc, 32)
      MFM(B0, B1, B2, B3, wsrc, 48)
      mlpB[u] = (a0 + a1) + (a2 + a3);
    }
    __syncthreads();                       // B_c: MLP partials visible

    // ---- phase D: every thread combines ye for BOTH its elements; owners do loss;
    //      each wave refreshes its own window copy (no trailing barrier) ----
    {
      float ye_l = (mlpB[l]      + mlpB[128 + l]) + bias_l;
      float ye_h = (mlpB[64 + l] + mlpB[192 + l]) + bias_h;
      float df_l = ye_l - ylo, df_h = ye_h - yhi;
      if (w == 0 && !mask_l) lossAcc = fmaf(df_l, df_l, lossAcc);
      if (w == 1 && !mask_h) lossAcc = fmaf(df_h, df_h, lossAcc);
      ylo -= ye_l; yhi -= ye_h;
      ydw[128 + l] = ylo; ydw[192 + l] = yhi; ydw[256 + l] = ylo; ydw[320 + l] = yhi;
    }
  }

  // ---- block loss/cnt, partial store + ticket; last block finalizes ----
  lossAcc = waveSum(lossAcc);
  cnt     = waveSum(cnt);
  if (l == 0){ sL[w] = lossAcc; sC[w] = cnt; }
  __syncthreads();
  if (u == 0){
    union { float2 f; unsigned long long v; } pk;
    pk.f.x = (sL[0] + sL[1]) + (sL[2] + sL[3]);
    pk.f.y = (sC[0] + sC[1]) + (sC[2] + sC[3]);
    __hip_atomic_store(&partials[blockIdx.x], pk.v, __ATOMIC_RELEASE, __HIP_MEMORY_SCOPE_AGENT);
    sOld = __hip_atomic_fetch_add(ticket, 1, __ATOMIC_ACQ_REL, __HIP_MEMORY_SCOPE_AGENT);
  }
  __syncthreads();
  if (sOld == NBLK - 1){
    float ls = 0.f, cs = 0.f;
    for (int g = u; g < NBLK; g += 256){
      union { float2 f; unsigned long long v; } pk;
      pk.v = __hip_atomic_load(&partials[g], __ATOMIC_ACQUIRE, __HIP_MEMORY_SCOPE_AGENT);
      ls += pk.f.x; cs += pk.f.y;
    }
    ls = waveSum(ls); cs = waveSum(cs);
    if (l == 0){ sL[w] = ls; sC[w] = cs; }
    __syncthreads();
    if (u == 0) out[0] = ((sL[0] + sL[1]) + (sL[2] + sL[3])) /
                         ((float)NITER * ((sC[0] + sC[1]) + (sC[2] + sC[3])));
  }
}

extern "C" void kernel_launch(void* const* d_in, const int* in_sizes, int n_in,
                              void* d_out, int out_size, void* d_ws, size_t ws_size,
                              hipStream_t stream){
  const float* x  = (const float*)d_in[0];
  const float* y  = (const float*)d_in[1];
  const float* w1 = (const float*)d_in[2];
  const float* b1 = (const float*)d_in[3];
  const float* w2 = (const float*)d_in[4];
  const float* b2 = (const float*)d_in[5];
  float* out = (float*)d_out;

  // ws: [0,4) ticket ; [256, 256+256K) M4 ; +2K biasT ; +16K partials
  int*   ticket = (int*)d_ws;
  float* M4     = (float*)((char*)d_ws + 256);
  float* biasT  = (float*)((char*)d_ws + 256 + 4 * 128 * 128 * sizeof(float));
  unsigned long long* partials =
      (unsigned long long*)((char*)d_ws + 256 + 4 * 128 * 128 * sizeof(float) + 4 * 128 * sizeof(float));

  prepK<<<517, 256, 0, stream>>>(w1, b1, w2, b2, M4, biasT, ticket);
  mainK<<<NBLK, 256, 0, stream>>>(x, y, M4, biasT, partials, ticket, out);
}

// Round 5
// 156.615 us; speedup vs baseline: 1.0525x; 1.0525x over previous
//
#include <hip/hip_runtime.h>
#include <math.h>

// B=4, T=512, IDIM=128, HDIM=1024, CDIM=256
#define NBLK  2048            // one row per block, 2 waves per block
#define NITER 4
#define IGNORE_OUT 10000.0f
#define LOG2E 1.44269504088896340736f

__device__ __forceinline__ float readlanef(float v, int lane){
  return __int_as_float(__builtin_amdgcn_readlane(__float_as_int(v), lane));
}

// ---- DPP wave primitives (gfx9 ladder: row_shr 1/2/4/8, bcast15->rows1,3, bcast31->rows2,3) ----
__device__ __forceinline__ float waveScanInc(float v){
  v += __int_as_float(__builtin_amdgcn_update_dpp(0, __float_as_int(v), 0x111, 0xF, 0xF, true));
  v += __int_as_float(__builtin_amdgcn_update_dpp(0, __float_as_int(v), 0x112, 0xF, 0xF, true));
  v += __int_as_float(__builtin_amdgcn_update_dpp(0, __float_as_int(v), 0x114, 0xF, 0xF, true));
  v += __int_as_float(__builtin_amdgcn_update_dpp(0, __float_as_int(v), 0x118, 0xF, 0xF, true));
  v += __int_as_float(__builtin_amdgcn_update_dpp(0, __float_as_int(v), 0x142, 0xA, 0xF, true));
  v += __int_as_float(__builtin_amdgcn_update_dpp(0, __float_as_int(v), 0x143, 0xC, 0xF, true));
  return v;                                // lane l = sum of lanes 0..l
}
__device__ __forceinline__ float waveSum(float v){
  return readlanef(waveScanInc(v), 63);
}
__device__ __forceinline__ void waveArgmax(float &v, int &i){
#define AMSTEP(ctrl, rm) { \
    float ov = __int_as_float(__builtin_amdgcn_update_dpp(__float_as_int(v), __float_as_int(v), ctrl, rm, 0xF, false)); \
    int   oi = __builtin_amdgcn_update_dpp(i, i, ctrl, rm, 0xF, false); \
    bool take = (ov > v) || (ov == v && oi < i); \
    v = take ? ov : v; i = take ? oi : i; }
  AMSTEP(0x111, 0xF) AMSTEP(0x112, 0xF) AMSTEP(0x114, 0xF)
  AMSTEP(0x118, 0xF) AMSTEP(0x142, 0xA) AMSTEP(0x143, 0xC)
#undef AMSTEP
  v = readlanef(v, 63);
  i = __builtin_amdgcn_readlane(i, 63);
}
// paired gather: a = vec[idx], b = vec[idx+64] (0 outside [0,128)); 2 bpermutes total
__device__ __forceinline__ void gatherPair(float v0, float v1, int idx, float &a, float &b){
  int c = idx & 63;
  float g0 = __shfl(v0, c, 64);
  float g1 = __shfl(v1, c, 64);
  a = ((unsigned)idx < 128u) ? ((idx & 64) ? g1 : g0) : 0.f;
  int idx2 = idx + 64;
  b = ((unsigned)idx2 < 128u) ? ((idx2 & 64) ? g1 : g0) : 0.f;
}

// ---------- prep kernel: M4[i] = w2[:, i*256:(i+1)*256] @ w1[i*256:(i+1)*256, :] ----------
// Latency-tolerant version: 512 threads/block, q = tid>>7 splits the 256-deep K range
// into QUARTERS (64-deep dots, 4 independent chains of 16 each), LDS tree combine.
// 517 blocks x 8 waves -> ~4k waves resident (vs ~2k effective before): the old prepK
// was pure latency exposure (~60us for 33 MFLOP) at 2 waves/SIMD.
__global__ __launch_bounds__(512)
void prepK(const float* __restrict__ w1, const float* __restrict__ b1,
           const float* __restrict__ w2, const float* __restrict__ b2,
           float* __restrict__ M4, float* __restrict__ biasT, int* __restrict__ ticket){
  const int blk = blockIdx.x;
  const int tid = threadIdx.x;
  const int u = tid & 127, q = tid >> 7;   // u = output-row/col, q = K-quarter 0..3
  __shared__ float part[512];
  if (blk < 512){
    int i = blk >> 7, o = blk & 127;
    const float* w1p = w1 + (i * 256 + q * 64) * 128 + u;   // coalesced over d=u
    const float* w2p = w2 + o * 1024 + i * 256 + q * 64;    // wave-uniform
    float a0 = 0.f, a1 = 0.f, a2 = 0.f, a3 = 0.f;
    #pragma unroll
    for (int c = 0; c < 64; c += 4){
      a0 = fmaf(w1p[(c + 0) * 128], w2p[c + 0], a0);
      a1 = fmaf(w1p[(c + 1) * 128], w2p[c + 1], a1);
      a2 = fmaf(w1p[(c + 2) * 128], w2p[c + 2], a2);
      a3 = fmaf(w1p[(c + 3) * 128], w2p[c + 3], a3);
    }
    part[tid] = (a0 + a1) + (a2 + a3);
    __syncthreads();
    if (q == 0)
      M4[i * 16384 + (u >> 2) * 512 + o * 4 + (u & 3)] =
          (part[u] + part[128 + u]) + (part[256 + u] + part[384 + u]);
  } else if (blk < 516){
    int i = blk - 512;
    const float* w2p = w2 + u * 1024 + i * 256 + q * 64;
    const float* b1p = b1 + i * 256 + q * 64;
    float a0 = (q == 0) ? b2[u] : 0.f, a1 = 0.f, a2 = 0.f, a3 = 0.f;
    #pragma unroll
    for (int c = 0; c < 64; c += 4){
      a0 = fmaf(b1p[c + 0], w2p[c + 0], a0);
      a1 = fmaf(b1p[c + 1], w2p[c + 1], a1);
      a2 = fmaf(b1p[c + 2], w2p[c + 2], a2);
      a3 = fmaf(b1p[c + 3], w2p[c + 3], a3);
    }
    part[tid] = (a0 + a1) + (a2 + a3);
    __syncthreads();
    if (q == 0)
      biasT[i * 128 + u] = (part[u] + part[128 + u]) + (part[256 + u] + part[384 + u]);
  } else {
    if (tid == 0) *ticket = 0;
  }
}

// M-group load/consume macros — NAMED float4 scalars only (no arrays: spill-proof).
// Group gg covers M float4-rows 4gg..4gg+3 = k-values 16gg..16gg+15.
#define MLD(d0, d1, d2, d3, gg) \
  d0 = Mp[((gg) * 4 + 0) * 128 + u]; d1 = Mp[((gg) * 4 + 1) * 128 + u]; \
  d2 = Mp[((gg) * 4 + 2) * 128 + u]; d3 = Mp[((gg) * 4 + 3) * 128 + u];
#define MFM(m0, m1, m2, m3, src, kb) \
  a0 = fmaf((m0).x, readlanef(src, (kb) + 0), a0);  a0 = fmaf((m0).y, readlanef(src, (kb) + 1), a0); \
  a0 = fmaf((m0).z, readlanef(src, (kb) + 2), a0);  a0 = fmaf((m0).w, readlanef(src, (kb) + 3), a0); \
  a1 = fmaf((m1).x, readlanef(src, (kb) + 4), a1);  a1 = fmaf((m1).y, readlanef(src, (kb) + 5), a1); \
  a1 = fmaf((m1).z, readlanef(src, (kb) + 6), a1);  a1 = fmaf((m1).w, readlanef(src, (kb) + 7), a1); \
  a2 = fmaf((m2).x, readlanef(src, (kb) + 8), a2);  a2 = fmaf((m2).y, readlanef(src, (kb) + 9), a2); \
  a2 = fmaf((m2).z, readlanef(src, (kb) +10), a2);  a2 = fmaf((m2).w, readlanef(src, (kb) +11), a2); \
  a3 = fmaf((m3).x, readlanef(src, (kb) +12), a3);  a3 = fmaf((m3).y, readlanef(src, (kb) +13), a3); \
  a3 = fmaf((m3).z, readlanef(src, (kb) +14), a3);  a3 = fmaf((m3).w, readlanef(src, (kb) +15), a3);

// ---------- main kernel: round-3 version verbatim (measured 88.8us, VGPR 56, no spill) ----------
// wave w handles shift-pair t = 64w + l (shifts t and t+128), full j range [0,128)
// window value for (t, j) = y[(255 - t + j) % 128] = yd[(255 - t) + j], yd[384] duplicated
__global__ __launch_bounds__(128, 4)
void mainK(const float* __restrict__ x, const float* __restrict__ y,
           const float* __restrict__ M4, const float* __restrict__ biasT,
           unsigned long long* __restrict__ partials, int* __restrict__ ticket,
           float* __restrict__ out){
  __shared__ float yd[384];     // yd[128+k] = yd[256+k] = y_res[k]
  __shared__ float sVal[2];
  __shared__ int   sIdx[2];
  __shared__ float sL[2], sC[2];
  __shared__ int   sOld;

  const int u = threadIdx.x;               // 0..127 ; u = 64w + l = owned element / output
  const int l = u & 63;
  const int w = u >> 6;
  const long base = (long)blockIdx.x * 128;

  float xlo = x[base + l], xhi = x[base + 64 + l];
  float ylo = y[base + l], yhi = y[base + 64 + l];
  const float yOwn0 = w ? yhi : ylo;
  const bool mOwn = (yOwn0 == IGNORE_OUT);
  float cnt = mOwn ? 0.f : 1.f;
  float lossAcc = 0.f;

  yd[128 + u] = yOwn0; yd[256 + u] = yOwn0;
  __syncthreads();

  for (int i = 0; i < NITER; ++i){
    const float4* Mp = (const float4*)(M4 + (size_t)i * 16384);

    // ---- window-norm prefix at t = 64w+l (DPP scan + DPP sums; zero DS) ----
    float own2 = w ? xhi * xhi : xlo * xlo;
    float oth2 = w ? xlo * xlo : xhi * xhi;
    float v = waveScanInc(own2);
    float osum  = waveSum(oth2);
    float total = readlanef(v, 63) + osum;
    float pref_t = w ? (v + osum) : v;     // inclusive prefix of x^2 at index t
    float ny2 = waveSum(ylo * ylo + yhi * yhi);

    // ---- corr: 128 b32 LDS window steps (2 lanes/bank = free), readlane broadcasts.
    //      Serial snap chain replaced by 4-way-split full sums + 4-way-split MASKED
    //      prefix ((l>=j)?w:0 cndmask) — all chains independent (~64cy vs ~450cy). ----
    const float* wp = yd + (255 - u);      // base in [128, 255]
    float s0=0.f,s1=0.f,s2=0.f,s3=0.f;     // first half  (j=0..63)  full sum
    float t0=0.f,t1=0.f,t2=0.f,t3=0.f;     // second half (j=64..127) full sum
    float p0=0.f,p1=0.f,p2=0.f,p3=0.f;     // masked prefix over own half
    if (w == 0){                           // t = l: prefix lives in first half
      #pragma unroll
      for (int j = 0; j < 64; j += 4){
        float wv0 = wp[j], wv1 = wp[j+1], wv2 = wp[j+2], wv3 = wp[j+3];
        float x0 = readlanef(xlo, j),   x1 = readlanef(xlo, j+1);
        float x2 = readlanef(xlo, j+2), x3 = readlanef(xlo, j+3);
        s0 = fmaf(wv0, x0, s0); s1 = fmaf(wv1, x1, s1);
        s2 = fmaf(wv2, x2, s2); s3 = fmaf(wv3, x3, s3);
        p0 = fmaf((l >= j    ) ? wv0 : 0.f, x0, p0);
        p1 = fmaf((l >= j + 1) ? wv1 : 0.f, x1, p1);
        p2 = fmaf((l >= j + 2) ? wv2 : 0.f, x2, p2);
        p3 = fmaf((l >= j + 3) ? wv3 : 0.f, x3, p3);
      }
      #pragma unroll
      for (int j = 0; j < 64; j += 4){
        float wv0 = wp[64+j], wv1 = wp[64+j+1], wv2 = wp[64+j+2], wv3 = wp[64+j+3];
        t0 = fmaf(wv0, readlanef(xhi, j),   t0);
        t1 = fmaf(wv1, readlanef(xhi, j+1), t1);
        t2 = fmaf(wv2, readlanef(xhi, j+2), t2);
        t3 = fmaf(wv3, readlanef(xhi, j+3), t3);
      }
    } else {                               // t = 64+l: first half all j<=t; prefix in second
      #pragma unroll
      for (int j = 0; j < 64; j += 4){
        float wv0 = wp[j], wv1 = wp[j+1], wv2 = wp[j+2], wv3 = wp[j+3];
        s0 = fmaf(wv0, readlanef(xlo, j),   s0);
        s1 = fmaf(wv1, readlanef(xlo, j+1), s1);
        s2 = fmaf(wv2, readlanef(xlo, j+2), s2);
        s3 = fmaf(wv3, readlanef(xlo, j+3), s3);
      }
      #pragma unroll
      for (int j = 0; j < 64; j += 4){
        float wv0 = wp[64+j], wv1 = wp[64+j+1], wv2 = wp[64+j+2], wv3 = wp[64+j+3];
        float x0 = readlanef(xhi, j),   x1 = readlanef(xhi, j+1);
        float x2 = readlanef(xhi, j+2), x3 = readlanef(xhi, j+3);
        t0 = fmaf(wv0, x0, t0); t1 = fmaf(wv1, x1, t1);
        t2 = fmaf(wv2, x2, t2); t3 = fmaf(wv3, x3, t3);
        p0 = fmaf((l >= j    ) ? wv0 : 0.f, x0, p0);
        p1 = fmaf((l >= j + 1) ? wv1 : 0.f, x1, p1);
        p2 = fmaf((l >= j + 2) ? wv2 : 0.f, x2, p2);
        p3 = fmaf((l >= j + 3) ? wv3 : 0.f, x3, p3);
      }
    }
    float Sh0 = (s0 + s1) + (s2 + s3);
    float Sh1 = (t0 + t1) + (t2 + t3);
    float P   = (p0 + p1) + (p2 + p3);
    float nt = Sh0 + Sh1;
    float n1 = w ? (Sh0 + P) : P;

    // ---- cosine sims via v_rsq; DPP argmax; cross-wave combine ----
    {
      bool yz = (ny2 == 0.f);
      float rNY = __builtin_amdgcn_rsqf(ny2);       // 1/||y||
      float nx2b = fmaxf(total - pref_t, 0.f);
      float s1v = (yz || pref_t == 0.f) ? 0.f : n1 * __builtin_amdgcn_rsqf(pref_t) * rNY;
      float s2v = (yz || nx2b  == 0.f) ? 0.f : (nt - n1) * __builtin_amdgcn_rsqf(nx2b) * rNY;
      if (u == 127) s2v = -INFINITY;       // shift 255 doesn't exist
      float bv = s1v; int bi = u;
      if (s2v > bv){ bv = s2v; bi = u + 128; }
      waveArgmax(bv, bi);
      if (l == 0){ sVal[w] = bv; sIdx[w] = bi; }
    }
    __syncthreads();                       // B1

    // ---- issue MLP groups 0,1 + bias: L2 latency hidden under argmax-combine +
    //      softmax + gathers; live ranges start HERE (never across corr/barriers) ----
    float4 A0, A1, A2, A3, B0, B1, B2, B3;
    MLD(A0, A1, A2, A3, 0)
    MLD(B0, B1, B2, B3, 1)
    float bias_i = biasT[i * 128 + u];

    int sstar;
    {
      float v0 = sVal[0], v1 = sVal[1];
      int   i0 = sIdx[0], i1 = sIdx[1];
      sstar = (v1 > v0 || (v1 == v0 && i1 < i0)) ? i1 : i0;
    }

    // ---- x_aug + detached softmax (hw exp2/rcp; paired gathers) ----
    float xa, xb;
    gatherPair(xlo, xhi, sstar + l - 127, xa, xb);
    float ea = __builtin_amdgcn_exp2f(xa * ylo * LOG2E);
    float eb = __builtin_amdgcn_exp2f(xb * yhi * LOG2E);
    float rse = __builtin_amdgcn_rcpf(waveSum(ea + eb));
    float wlo = xa * (ea * rse), whi = xb * (eb * rse);   // xatt

    // ---- x_res update (reverse shift, paired gather) ----
    {
      float ga, gb;
      gatherPair(wlo, whi, l + 127 - sstar, ga, gb);
      xlo -= ga; xhi -= gb;
    }

    // ---- MLP: thread u -> output o = u; 2 rotating named-reg buffers (32 VGPRs),
    //      one-group-ahead prefetch; accumulation order identical to r11 baseline ----
    float ye;
    {
      float a0 = 0.f, a1 = 0.f, a2 = 0.f, a3 = 0.f;
      MFM(A0, A1, A2, A3, wlo, 0)   MLD(A0, A1, A2, A3, 2)
      MFM(B0, B1, B2, B3, wlo, 16)  MLD(B0, B1, B2, B3, 3)
      MFM(A0, A1, A2, A3, wlo, 32)  MLD(A0, A1, A2, A3, 4)
      MFM(B0, B1, B2, B3, wlo, 48)  MLD(B0, B1, B2, B3, 5)
      MFM(A0, A1, A2, A3, whi, 0)   MLD(A0, A1, A2, A3, 6)
      MFM(B0, B1, B2, B3, whi, 16)  MLD(B0, B1, B2, B3, 7)
      MFM(A0, A1, A2, A3, whi, 32)
      MFM(B0, B1, B2, B3, whi, 48)
      ye = ((a0 + a1) + (a2 + a3)) + bias_i;
    }

    // ---- loss on owned element + publish new y_res ----
    {
      float yOwn = w ? yhi : ylo;
      float df = ye - yOwn;
      if (!mOwn) lossAcc = fmaf(df, df, lossAcc);
      float yNew = yOwn - ye;
      yd[128 + u] = yNew; yd[256 + u] = yNew;
    }
    __syncthreads();                       // B2
    ylo = yd[128 + l];                     // refresh register copies from yd
    yhi = yd[192 + l];
  }

  // ---- block loss/cnt, partial store + ticket; last block finalizes ----
  lossAcc = waveSum(lossAcc);
  cnt     = waveSum(cnt);
  if (l == 0){ sL[w] = lossAcc; sC[w] = cnt; }
  __syncthreads();
  if (u == 0){
    union { float2 f; unsigned long long v; } pk;
    pk.f.x = sL[0] + sL[1];
    pk.f.y = sC[0] + sC[1];
    __hip_atomic_store(&partials[blockIdx.x], pk.v, __ATOMIC_RELEASE, __HIP_MEMORY_SCOPE_AGENT);
    sOld = __hip_atomic_fetch_add(ticket, 1, __ATOMIC_ACQ_REL, __HIP_MEMORY_SCOPE_AGENT);
  }
  __syncthreads();
  if (sOld == NBLK - 1){
    float ls = 0.f, cs = 0.f;
    for (int g = u; g < NBLK; g += 128){
      union { float2 f; unsigned long long v; } pk;
      pk.v = __hip_atomic_load(&partials[g], __ATOMIC_ACQUIRE, __HIP_MEMORY_SCOPE_AGENT);
      ls += pk.f.x; cs += pk.f.y;
    }
    ls = waveSum(ls); cs = waveSum(cs);
    if (l == 0){ sL[w] = ls; sC[w] = cs; }
    __syncthreads();
    if (u == 0) out[0] = (sL[0] + sL[1]) / ((float)NITER * (sC[0] + sC[1]));
  }
}

extern "C" void kernel_launch(void* const* d_in, const int* in_sizes, int n_in,
                              void* d_out, int out_size, void* d_ws, size_t ws_size,
                              hipStream_t stream){
  const float* x  = (const float*)d_in[0];
  const float* y  = (const float*)d_in[1];
  const float* w1 = (const float*)d_in[2];
  const float* b1 = (const float*)d_in[3];
  const float* w2 = (const float*)d_in[4];
  const float* b2 = (const float*)d_in[5];
  float* out = (float*)d_out;

  // ws: [0,4) ticket ; [256, 256+256K) M4 ; +2K biasT ; +16K partials
  int*   ticket = (int*)d_ws;
  float* M4     = (float*)((char*)d_ws + 256);
  float* biasT  = (float*)((char*)d_ws + 256 + 4 * 128 * 128 * sizeof(float));
  unsigned long long* partials =
      (unsigned long long*)((char*)d_ws + 256 + 4 * 128 * 128 * sizeof(float) + 4 * 128 * sizeof(float));

  prepK<<<517, 512, 0, stream>>>(w1, b1, w2, b2, M4, biasT, ticket);
  mainK<<<NBLK, 128, 0, stream>>>(x, y, M4, biasT, partials, ticket, out);
}